// Round 11
// baseline (150.478 us; speedup 1.0000x reference)
//
#include <hip/hip_runtime.h>
#include <float.h>

#define TSEQ 4096
#define CEMB 1024
#define NH 64
#define WIN 256

typedef __attribute__((ext_vector_type(8))) short  s16x8;
typedef __attribute__((ext_vector_type(4))) float  f32x4;
typedef unsigned short ush;

// Truncation-based fp32 -> bf16 hi/lo split. |x - (hi+lo)| <= 2^-16 |x|.
__device__ __forceinline__ void split2(float f, ush& hi, ush& lo) {
    unsigned b = __float_as_uint(f);
    hi = (ush)(b >> 16);
    float hf = __uint_as_float(b & 0xFFFF0000u);
    lo = (ush)(__float_as_uint(f - hf) >> 16);
}

__device__ __forceinline__ void split8(f32x4 a, f32x4 b, s16x8& hi, s16x8& lo) {
    #pragma unroll
    for (int j = 0; j < 4; ++j) { ush h, l; split2(a[j], h, l); hi[j] = (short)h; lo[j] = (short)l; }
    #pragma unroll
    for (int j = 0; j < 4; ++j) { ush h, l; split2(b[j], h, l); hi[4+j] = (short)h; lo[4+j] = (short)l; }
}

#define MFMA(a, b, c) __builtin_amdgcn_mfma_f32_16x16x32_bf16((a), (b), (c), 0, 0, 0)

// ============ W convert+transpose: W[1024][64] f32 -> Wt[n][k] bf16 hi/lo ============
__global__ __launch_bounds__(256)
void w_convert(const float* __restrict__ Wk, const float* __restrict__ Wq,
               const float* __restrict__ Wv,
               ush* __restrict__ Wth, ush* __restrict__ Wtl)
{
    __shared__ ush Lh[64][66], Ll[64][66];
    const int m  = blockIdx.x >> 4;
    const int k0 = (blockIdx.x & 15) << 6;
    const float* src = (m == 0) ? Wk : ((m == 1) ? Wq : Wv);

    const int kr = threadIdx.x >> 2;
    const int cq = threadIdx.x & 3;
    #pragma unroll
    for (int j = 0; j < 4; ++j) {
        const f32x4 v = *(const f32x4*)&src[(k0 + kr) * NH + cq * 16 + j * 4];
        #pragma unroll
        for (int e = 0; e < 4; ++e) {
            ush h, l; split2(v[e], h, l);
            const int c = cq * 16 + j * 4 + e;
            Lh[c][kr] = h; Ll[c][kr] = l;
        }
    }
    __syncthreads();
    const int n  = threadIdx.x >> 2;
    const int kc = threadIdx.x & 3;
    const size_t ob = (size_t)(m * 64 + n) * CEMB + k0 + kc * 16;
    *(s16x8*)&Wth[ob]     = *(const s16x8*)&Lh[n][kc * 16];
    *(s16x8*)&Wth[ob + 8] = *(const s16x8*)&Lh[n][kc * 16 + 8];
    *(s16x8*)&Wtl[ob]     = *(const s16x8*)&Ll[n][kc * 16];
    *(s16x8*)&Wtl[ob + 8] = *(const s16x8*)&Ll[n][kc * 16 + 8];
}

// ============ QKV projection: M-tile 32, BK=64, 2-deep reg-staged x, split-on-write ============
// A LDS: bf16 h/l [2 buf][32 rows][8 chunks of 8], chunk' = chunk ^ (row&7).
// B LDS: bf16 h/l [192 n][8 chunks of 8], chunk' = chunk ^ (n&7), single-buffered, W 1-deep (L2-hot).
__global__ __launch_bounds__(256)
void qkv_proj(const float* __restrict__ x,
              const ush* __restrict__ Wth, const ush* __restrict__ Wtl,
              ush* __restrict__ kbh, ush* __restrict__ kbl,
              ush* __restrict__ qbh, ush* __restrict__ qbl,
              ush* __restrict__ vbh, ush* __restrict__ vbl)
{
    __shared__ ush Ah[2][32 * 64], Al[2][32 * 64];
    __shared__ ush Bh[192 * 64], Bl[192 * 64];

    const int tid = threadIdx.x;
    const int m0  = blockIdx.x << 5;
    const int w   = tid >> 6;
    const int l15 = tid & 15;
    const int g   = (tid >> 4) & 3;

    // A stage map: row = tid>>3, chunk = tid&7 (8 bf16 each)
    const int arow = tid >> 3;
    const int ach  = tid & 7;
    const float* xp = x + (size_t)(m0 + arow) * CEMB + ach * 8;
    const int awo = arow * 64 + ((ach ^ (arow & 7)) << 3);

    // B stage map: 6 slots/thread
    int bn[6], bc[6], bwo[6];
    #pragma unroll
    for (int i = 0; i < 6; ++i) {
        const int s = tid + (i << 8);
        bn[i] = s >> 3; bc[i] = s & 7;
        bwo[i] = bn[i] * 64 + ((bc[i] ^ (bn[i] & 7)) << 3);
    }

    f32x4 acc[2][3];
    #pragma unroll
    for (int i = 0; i < 2; ++i)
        #pragma unroll
        for (int j = 0; j < 3; ++j) acc[i][j] = (f32x4){0.f, 0.f, 0.f, 0.f};

    f32x4 xA0, xA1, xB0, xB1;       // named ping-pong x-stage regs (even/odd tiles)
    s16x8 wrh[6], wrl[6];

    // prologue: A(0) -> LDS buf0; load x(1) regs; load W(0) regs
    xA0 = *(const f32x4*)(xp);
    xA1 = *(const f32x4*)(xp + 4);
    { s16x8 vh, vl; split8(xA0, xA1, vh, vl);
      *(s16x8*)&Ah[0][awo] = vh; *(s16x8*)&Al[0][awo] = vl; }
    xB0 = *(const f32x4*)(xp + 64);
    xB1 = *(const f32x4*)(xp + 68);
    #pragma unroll
    for (int i = 0; i < 6; ++i) {
        const size_t o = (size_t)bn[i] * CEMB + bc[i] * 8;
        wrh[i] = *(const s16x8*)&Wth[o];
        wrl[i] = *(const s16x8*)&Wtl[o];
    }

#define QKV_BODY(T, CUR, NXT, XW0, XW1, XL0, XL1)                                   \
    {                                                                               \
        _Pragma("unroll")                                                           \
        for (int i = 0; i < 6; ++i) {                                               \
            *(s16x8*)&Bh[bwo[i]] = wrh[i];                                          \
            *(s16x8*)&Bl[bwo[i]] = wrl[i];                                          \
        }                                                                           \
        if ((T) < 15) {                                                             \
            s16x8 vh, vl; split8(XW0, XW1, vh, vl);                                 \
            *(s16x8*)&Ah[NXT][awo] = vh; *(s16x8*)&Al[NXT][awo] = vl;               \
        }                                                                           \
        __syncthreads();                                                            \
        if ((T) < 14) {                                                             \
            XL0 = *(const f32x4*)(xp + ((T) + 2) * 64);                             \
            XL1 = *(const f32x4*)(xp + ((T) + 2) * 64 + 4);                         \
        }                                                                           \
        if ((T) < 15) {                                                             \
            _Pragma("unroll")                                                       \
            for (int i = 0; i < 6; ++i) {                                           \
                const size_t o = (size_t)bn[i] * CEMB + ((T) + 1) * 64 + bc[i] * 8; \
                wrh[i] = *(const s16x8*)&Wth[o];                                    \
                wrl[i] = *(const s16x8*)&Wtl[o];                                    \
            }                                                                       \
        }                                                                           \
        _Pragma("unroll")                                                           \
        for (int ks = 0; ks < 2; ++ks) {                                            \
            s16x8 afh[2], afl[2], bfh[3], bfl[3];                                   \
            _Pragma("unroll")                                                       \
            for (int rt = 0; rt < 2; ++rt) {                                        \
                const int o = (rt * 16 + l15) * 64 + (((ks * 4 + g) ^ (l15 & 7)) << 3); \
                afh[rt] = *(const s16x8*)&Ah[CUR][o];                               \
                afl[rt] = *(const s16x8*)&Al[CUR][o];                               \
            }                                                                       \
            _Pragma("unroll")                                                       \
            for (int ct = 0; ct < 3; ++ct) {                                        \
                const int n = w * 48 + ct * 16 + l15;                               \
                const int o = n * 64 + (((ks * 4 + g) ^ (n & 7)) << 3);             \
                bfh[ct] = *(const s16x8*)&Bh[o];                                    \
                bfl[ct] = *(const s16x8*)&Bl[o];                                    \
            }                                                                       \
            __builtin_amdgcn_s_setprio(1);                                          \
            _Pragma("unroll")                                                       \
            for (int rt = 0; rt < 2; ++rt)                                          \
                _Pragma("unroll")                                                   \
                for (int ct = 0; ct < 3; ++ct) {                                    \
                    acc[rt][ct] = MFMA(afh[rt], bfh[ct], acc[rt][ct]);              \
                    acc[rt][ct] = MFMA(afh[rt], bfl[ct], acc[rt][ct]);              \
                    acc[rt][ct] = MFMA(afl[rt], bfh[ct], acc[rt][ct]);              \
                }                                                                   \
            __builtin_amdgcn_s_setprio(0);                                          \
        }                                                                           \
        __syncthreads();                                                            \
    }

    for (int tp = 0; tp < 8; ++tp) {
        const int t0 = tp * 2;
        QKV_BODY(t0,     0, 1, xB0, xB1, xA0, xA1)
        QKV_BODY(t0 + 1, 1, 0, xA0, xA1, xB0, xB1)
    }
#undef QKV_BODY

    // epilogue: C/D row = g*4+r, col = l15
    #pragma unroll
    for (int ct = 0; ct < 3; ++ct) {
        const int colbase = w * 48 + ct * 16;
        ush *oph, *opl;
        if (colbase < 64)       { oph = kbh; opl = kbl; }
        else if (colbase < 128) { oph = qbh; opl = qbl; }
        else                    { oph = vbh; opl = vbl; }
        const int col = (colbase & 63) + l15;
        #pragma unroll
        for (int rt = 0; rt < 2; ++rt)
            #pragma unroll
            for (int r = 0; r < 4; ++r) {
                const size_t row = m0 + rt * 16 + g * 4 + r;
                ush h, l; split2(acc[rt][ct][r], h, l);
                oph[row * NH + col] = h;
                opl[row * NH + col] = l;
            }
    }
}

// ============ V transpose: vb[b*T][64] -> vbT[(b*64+dim)][T] ============
__global__ __launch_bounds__(256)
void v_transpose(const ush* __restrict__ vbh, const ush* __restrict__ vbl,
                 ush* __restrict__ vbTh, ush* __restrict__ vbTl)
{
    __shared__ ush Th[64][72], Tl[64][72];
    const int k0 = blockIdx.x << 6;
    const int b  = blockIdx.y;
    const int key = threadIdx.x >> 2;
    const int cp  = (threadIdx.x & 3) << 1;
    #pragma unroll
    for (int i = 0; i < 2; ++i) {
        const int c = cp + i;
        const size_t o = ((size_t)b * TSEQ + k0 + key) * NH + c * 8;
        const s16x8 h = *(const s16x8*)&vbh[o];
        const s16x8 l = *(const s16x8*)&vbl[o];
        #pragma unroll
        for (int j = 0; j < 8; ++j) {
            Th[c * 8 + j][key] = (ush)h[j];
            Tl[c * 8 + j][key] = (ush)l[j];
        }
    }
    __syncthreads();
    const int dim = threadIdx.x >> 2;
    const int kc  = threadIdx.x & 3;
    const size_t ob = ((size_t)b * 64 + dim) * TSEQ + k0 + kc * 16;
    *(s16x8*)&vbTh[ob]     = *(const s16x8*)&Th[dim][kc * 16];
    *(s16x8*)&vbTh[ob + 8] = *(const s16x8*)&Th[dim][kc * 16 + 8];
    *(s16x8*)&vbTl[ob]     = *(const s16x8*)&Tl[dim][kc * 16];
    *(s16x8*)&vbTl[ob + 8] = *(const s16x8*)&Tl[dim][kc * 16 + 8];
}

// ============ Sliding-window attention: Q-tile 32, 2-way window-split, 2/SIMD occupancy ============
// 4 waves: rg = w&1 (row-group), hf = w>>1 (window half). K direct-global (L2-hot),
// V^T double-buffered LDS with issue-early/write-late staging, 2-way (m,l,O) merge.
__global__ __launch_bounds__(256)
void attn_swin(const ush* __restrict__ qbh, const ush* __restrict__ qbl,
               const ush* __restrict__ kbh, const ush* __restrict__ kbl,
               const ush* __restrict__ vbTh, const ush* __restrict__ vbTl,
               float* __restrict__ out)
{
    __shared__ ush Vth[2][64 * 72], Vtl[2][64 * 72];
    __shared__ ush Ph[4][16 * 64], Pl[4][16 * 64];
    __shared__ float cO[4][16][68];
    __shared__ float cmx[4][16], cls[4][16];

    const int tid = threadIdx.x;
    const int q0  = blockIdx.x << 5;
    const int b   = blockIdx.y;
    const size_t tb = (size_t)b * TSEQ;
    const int w   = tid >> 6;
    const int l15 = tid & 15;
    const int g   = (tid >> 4) & 3;
    const int u   = l15 & 7;
    const int rg  = w & 1;
    const int hf  = w >> 1;

    const int qrow = q0 + rg * 16 + l15;

    s16x8 Qh[2], Ql[2];
    #pragma unroll
    for (int ks = 0; ks < 2; ++ks) {
        const size_t o = (tb + qrow) * NH + ks * 32 + g * 8;
        Qh[ks] = *(const s16x8*)&qbh[o];
        Ql[ks] = *(const s16x8*)&qbl[o];
    }

    f32x4 O[4];
    #pragma unroll
    for (int i = 0; i < 4; ++i) O[i] = (f32x4){0.f, 0.f, 0.f, 0.f};
    float m_run = -FLT_MAX, l_run = 0.f;

    int lo = q0 - (WIN - 1); if (lo < 0) lo = 0;
    const int t_lo = lo >> 6, t_hi = (q0 + 31) >> 6;
    const int nIter = (t_hi - t_lo + 2) >> 1;

    // V stage mapping: threads [sb*128, sb*128+128) stage buffer sb (== their hf)
    const int sb = tid >> 7;
    const int j  = tid & 127;
    int sdim[4], sch[4];
    #pragma unroll
    for (int ii = 0; ii < 4; ++ii) {
        const int it = j + (ii << 7);
        sdim[ii] = it >> 3; sch[ii] = it & 7;
    }
    const size_t vrow = (size_t)b * 64;

    s16x8 vrh[4], vrl[4];
    int ts = t_lo + sb;
    bool sv = ts <= t_hi;
    if (sv) {
        #pragma unroll
        for (int ii = 0; ii < 4; ++ii) {
            const size_t o = (vrow + sdim[ii]) * TSEQ + ts * 64 + sch[ii] * 8;
            vrh[ii] = *(const s16x8*)&vbTh[o];
            vrl[ii] = *(const s16x8*)&vbTl[o];
        }
    }

    for (int i = 0; i < nIter; ++i) {
        // write staged V (regs -> LDS), waits vmcnt via compiler
        if (sv) {
            #pragma unroll
            for (int ii = 0; ii < 4; ++ii) {
                const int lo_ = sdim[ii] * 72 + sch[ii] * 8;
                *(s16x8*)&Vth[sb][lo_] = vrh[ii];
                *(s16x8*)&Vtl[sb][lo_] = vrl[ii];
            }
        }
        __syncthreads();
        // issue next V stage early (hidden under this iteration's compute)
        const int tsn = t_lo + sb + 2 * (i + 1);
        const bool svn = (i + 1 < nIter) && (tsn <= t_hi);
        if (svn) {
            #pragma unroll
            for (int ii = 0; ii < 4; ++ii) {
                const size_t o = (vrow + sdim[ii]) * TSEQ + tsn * 64 + sch[ii] * 8;
                vrh[ii] = *(const s16x8*)&vbTh[o];
                vrl[ii] = *(const s16x8*)&vbTl[o];
            }
        }

        const int t = t_lo + hf + 2 * i;
        if (t <= t_hi) {
            const int k0 = t << 6;

            // ---- S^T = K * Q^T, K A-frags direct from global (L2-resident)
            f32x4 S[4];
            __builtin_amdgcn_s_setprio(1);
            #pragma unroll
            for (int kt = 0; kt < 4; ++kt) {
                f32x4 s = (f32x4){0.f, 0.f, 0.f, 0.f};
                #pragma unroll
                for (int ks = 0; ks < 2; ++ks) {
                    const size_t o = (tb + k0 + kt * 16 + l15) * NH + ks * 32 + g * 8;
                    const s16x8 kah = *(const s16x8*)&kbh[o];
                    const s16x8 kal = *(const s16x8*)&kbl[o];
                    s = MFMA(kah, Qh[ks], s);
                    s = MFMA(kah, Ql[ks], s);
                    s = MFMA(kal, Qh[ks], s);
                }
                S[kt] = s;
            }
            __builtin_amdgcn_s_setprio(0);

            // ---- mask + online softmax (lane owns q-row)
            float mt = -FLT_MAX;
            #pragma unroll
            for (int kt = 0; kt < 4; ++kt)
                #pragma unroll
                for (int r = 0; r < 4; ++r) {
                    const int key = k0 + kt * 16 + g * 4 + r;
                    const float s = S[kt][r] * 0.125f;
                    S[kt][r] = s;
                    if ((key <= qrow) && (key > qrow - WIN)) mt = fmaxf(mt, s);
                }
            mt = fmaxf(mt, __shfl_xor(mt, 16));
            mt = fmaxf(mt, __shfl_xor(mt, 32));
            const float mn  = fmaxf(m_run, mt);
            const float fsc = __expf(m_run - mn);

            float sum = 0.f;
            #pragma unroll
            for (int kt = 0; kt < 4; ++kt) {
                const int c2 = ((kt * 2 + (g >> 1)) + u) & 7;
                const int abase = l15 * 64 + c2 * 8 + (g & 1) * 4;
                #pragma unroll
                for (int rp = 0; rp < 4; rp += 2) {
                    const int key0 = k0 + kt * 16 + g * 4 + rp;
                    const bool v0 = (key0     <= qrow) && (key0     > qrow - WIN);
                    const bool v1 = (key0 + 1 <= qrow) && (key0 + 1 > qrow - WIN);
                    const float p0 = v0 ? __expf(S[kt][rp]     - mn) : 0.f;
                    const float p1 = v1 ? __expf(S[kt][rp + 1] - mn) : 0.f;
                    sum += p0 + p1;
                    ush h0, lo0, h1, lo1;
                    split2(p0, h0, lo0); split2(p1, h1, lo1);
                    *(unsigned int*)&Ph[w][abase + rp] = (unsigned int)h0  | ((unsigned int)h1  << 16);
                    *(unsigned int*)&Pl[w][abase + rp] = (unsigned int)lo0 | ((unsigned int)lo1 << 16);
                }
            }
            sum += __shfl_xor(sum, 16);
            sum += __shfl_xor(sum, 32);
            l_run = l_run * fsc + sum;
            m_run = mn;

            float fr[4];
            #pragma unroll
            for (int r = 0; r < 4; ++r) fr[r] = __shfl(fsc, g * 4 + r);
            #pragma unroll
            for (int dt = 0; dt < 4; ++dt)
                #pragma unroll
                for (int r = 0; r < 4; ++r) O[dt][r] *= fr[r];

            // ---- O += P * V  (A = P rows, B = V^T rows from LDS buf hf)
            #pragma unroll
            for (int ks = 0; ks < 2; ++ks) {
                const int po = l15 * 64 + (((ks * 4 + g) + u) & 7) * 8;
                const s16x8 pah = *(const s16x8*)&Ph[w][po];
                const s16x8 pal = *(const s16x8*)&Pl[w][po];
                __builtin_amdgcn_s_setprio(1);
                #pragma unroll
                for (int dt = 0; dt < 4; ++dt) {
                    const int vo = (dt * 16 + l15) * 72 + ks * 32 + g * 8;
                    const s16x8 vh8 = *(const s16x8*)&Vth[hf][vo];
                    const s16x8 vl8 = *(const s16x8*)&Vtl[hf][vo];
                    O[dt] = MFMA(pah, vh8, O[dt]);
                    O[dt] = MFMA(pah, vl8, O[dt]);
                    O[dt] = MFMA(pal, vh8, O[dt]);
                }
                __builtin_amdgcn_s_setprio(0);
            }
        }
        __syncthreads();   // PV readers done before next V overwrite
        sv = svn; ts = tsn;
    }

    // ---- 2-way cross-half combine
    if (g == 0) { cmx[w][l15] = m_run; cls[w][l15] = l_run; }
    #pragma unroll
    for (int dt = 0; dt < 4; ++dt)
        #pragma unroll
        for (int r = 0; r < 4; ++r)
            cO[w][g * 4 + r][dt * 16 + l15] = O[dt][r];
    __syncthreads();

    {
        const int rg2 = w & 1, dh = w >> 1;   // wave merges rows rg2, dims [dh*32, dh*32+32)
        const float m0 = cmx[rg2][l15],     m1 = cmx[rg2 + 2][l15];
        const float L0 = cls[rg2][l15],     L1 = cls[rg2 + 2][l15];
        const float ms = fmaxf(m0, m1);
        const float f0 = __expf(m0 - ms), f1 = __expf(m1 - ms);
        const float rl = 1.0f / (f0 * L0 + f1 * L1);
        #pragma unroll
        for (int e2 = 0; e2 < 2; ++e2) {
            f32x4 o;
            #pragma unroll
            for (int e = 0; e < 4; ++e) {
                const int d = dh * 32 + g * 8 + e2 * 4 + e;
                o[e] = (f0 * cO[rg2][l15][d] + f1 * cO[rg2 + 2][l15][d]) * rl;
            }
            *(f32x4*)&out[(tb + q0 + rg2 * 16 + l15) * NH + dh * 32 + g * 8 + e2 * 4] = o;
        }
    }
}

extern "C" void kernel_launch(void* const* d_in, const int* in_sizes, int n_in,
                              void* d_out, int out_size, void* d_ws, size_t ws_size,
                              hipStream_t stream)
{
    const float* x  = (const float*)d_in[0];
    const float* Wk = (const float*)d_in[1];
    const float* Wq = (const float*)d_in[2];
    const float* Wv = (const float*)d_in[3];
    float* out = (float*)d_out;

    const int Bn = in_sizes[0] / (TSEQ * CEMB);
    const size_t perBuf = (size_t)Bn * TSEQ * NH;

    ush* base = (ush*)d_ws;
    ush* kbh = base;
    ush* kbl = kbh + perBuf;
    ush* qbh = kbl + perBuf;
    ush* qbl = qbh + perBuf;
    ush* vbh = qbl + perBuf;
    ush* vbl = vbh + perBuf;
    ush* vbTh = vbl + perBuf;
    ush* vbTl = vbTh + perBuf;
    ush* Wth = vbTl + perBuf;
    ush* Wtl = Wth + 192 * CEMB;

    w_convert<<<dim3(48), dim3(256), 0, stream>>>(Wk, Wq, Wv, Wth, Wtl);
    qkv_proj<<<dim3((Bn * TSEQ) / 32), dim3(256), 0, stream>>>(x, Wth, Wtl,
                                                               kbh, kbl, qbh, qbl, vbh, vbl);
    v_transpose<<<dim3(TSEQ / 64, Bn), dim3(256), 0, stream>>>(vbh, vbl, vbTh, vbTl);
    attn_swin<<<dim3(TSEQ / 32, Bn), dim3(256), 0, stream>>>(qbh, qbl, kbh, kbl,
                                                             vbTh, vbTl, out);
}